// Round 8
// baseline (45.202 us; speedup 1.0000x reference)
//
#include <hip/hip_runtime.h>
#include <math.h>

// Sampler: iterative Gumbel-softmax relaxed top-k.
// att: [B=256, N=1024, M=4] f32; k=128; out: khot [B,N,M] f32.
// One WAVE per (b,m) column (64 lanes x 16 elems as 8 packed float2).
// Wall time = 128 x loop-carried chain (serial softmax iterations).
// This version fills the reduce-window bubbles: o[] is materialized so
// kh += o_prev schedules into the NEXT iteration's DPP/readlane/rcp
// latency shadow, and the cross-lane reduce runs as 4 interleaved DPP
// chains (covers DPP forwarding hazards).
// w carries exp(2*ag - M0) exactly (verified R4-R7).
// PRNG: JAX threefry2x32 key (0,42), partitionable: counter (0,i),
// bits = out0 ^ out1 (verified R4).

#define N_NODES 1024

typedef float f2 __attribute__((ext_vector_type(2)));

__device__ __forceinline__ unsigned rotl32(unsigned x, int r) {
  return (x << r) | (x >> (32 - r));
}

// JAX/Random123 Threefry-2x32, 20 rounds.
__device__ __forceinline__ void threefry2x32(unsigned k0, unsigned k1,
                                             unsigned& x0, unsigned& x1) {
  const unsigned ks0 = k0, ks1 = k1, ks2 = k0 ^ k1 ^ 0x1BD11BDAu;
  x0 += ks0; x1 += ks1;
  x0 += x1; x1 = rotl32(x1, 13); x1 ^= x0;
  x0 += x1; x1 = rotl32(x1, 15); x1 ^= x0;
  x0 += x1; x1 = rotl32(x1, 26); x1 ^= x0;
  x0 += x1; x1 = rotl32(x1, 6);  x1 ^= x0;
  x0 += ks1; x1 += ks2 + 1u;
  x0 += x1; x1 = rotl32(x1, 17); x1 ^= x0;
  x0 += x1; x1 = rotl32(x1, 29); x1 ^= x0;
  x0 += x1; x1 = rotl32(x1, 16); x1 ^= x0;
  x0 += x1; x1 = rotl32(x1, 24); x1 ^= x0;
  x0 += ks2; x1 += ks0 + 2u;
  x0 += x1; x1 = rotl32(x1, 13); x1 ^= x0;
  x0 += x1; x1 = rotl32(x1, 15); x1 ^= x0;
  x0 += x1; x1 = rotl32(x1, 26); x1 ^= x0;
  x0 += x1; x1 = rotl32(x1, 6);  x1 ^= x0;
  x0 += ks0; x1 += ks1 + 3u;
  x0 += x1; x1 = rotl32(x1, 17); x1 ^= x0;
  x0 += x1; x1 = rotl32(x1, 29); x1 ^= x0;
  x0 += x1; x1 = rotl32(x1, 16); x1 ^= x0;
  x0 += x1; x1 = rotl32(x1, 24); x1 ^= x0;
  x0 += ks1; x1 += ks2 + 4u;
  x0 += x1; x1 = rotl32(x1, 13); x1 ^= x0;
  x0 += x1; x1 = rotl32(x1, 15); x1 ^= x0;
  x0 += x1; x1 = rotl32(x1, 26); x1 ^= x0;
  x0 += x1; x1 = rotl32(x1, 6);  x1 ^= x0;
  x0 += ks2; x1 += ks0 + 5u;
}

// --- DPP wave-64 reduction steps (VALU-rate; no LDS) -------------------------
template <int CTRL>
__device__ __forceinline__ float dpp_sum_step(float v) {
  int t = __builtin_amdgcn_update_dpp(0, __float_as_int(v), CTRL, 0xf, 0xf, true);
  return v + __int_as_float(t);
}
template <int CTRL>
__device__ __forceinline__ float dpp_max_step(float v) {
  int iv = __float_as_int(v);
  int t = __builtin_amdgcn_update_dpp(iv, iv, CTRL, 0xf, 0xf, false);
  return fmaxf(v, __int_as_float(t));
}

__device__ __forceinline__ float wave_max64(float v) {
  v = dpp_max_step<0x111>(v);
  v = dpp_max_step<0x112>(v);
  v = dpp_max_step<0x114>(v);
  v = dpp_max_step<0x118>(v);
  v = dpp_max_step<0x142>(v);
  v = dpp_max_step<0x143>(v);
  return __int_as_float(__builtin_amdgcn_readlane(__float_as_int(v), 63));
}

__global__ __launch_bounds__(64)
void Sampler_72619307040792_kernel(const float* __restrict__ att,
                                   const int* __restrict__ kp,
                                   float* __restrict__ out) {
  const int col = blockIdx.x;        // 0..1023 = b*4 + m; ONE wave per column
  const int b = col >> 2;
  const int m = col & 3;
  const int lane = threadIdx.x;      // 64 threads = 1 wave
  const int k = *kp;

  const float EPS = __uint_as_float(0x00800000u);  // f32 tiny (normal min)
  const int base = b * 4096 + m;     // + n*4 indexes element n of this column

  float g[16];
  f2 w[8], kh[8], o[8];

  // --- init: att + Gumbel noise (threefry partitionable, bits = x0^x1), x2
#pragma unroll
  for (int j = 0; j < 16; ++j) {
    const int n = j * 64 + lane;
    const unsigned idx = (unsigned)(base + n * 4);
    unsigned c0 = 0u, c1 = idx;
    threefry2x32(0u, 42u, c0, c1);
    const unsigned bits = c0 ^ c1;
    const float u = __uint_as_float((bits >> 9) | 0x3F800000u) - 1.0f;
    const float gum = -logf(-logf(u + EPS));
    g[j] = 2.0f * (att[idx] + gum);
  }

  // --- column max M0 (uniform shift; exact softmax equivalence)
  float mx = g[0];
#pragma unroll
  for (int j = 1; j < 16; ++j) mx = fmaxf(mx, g[j]);
  mx = wave_max64(mx);

  // --- w = exp(g - M0) packed; kh = 0; o = 0 (so iter-0's kh-add is a no-op)
#pragma unroll
  for (int p = 0; p < 8; ++p) {
    f2 t;
    t.x = expf(g[2 * p] - mx);
    t.y = expf(g[2 * p + 1] - mx);
    w[p] = t;
    kh[p] = (f2)(0.0f);
    o[p] = (f2)(0.0f);
  }

  // --- k iterations.
  // Chain: tree(2) -> 4x interleaved DPP chains(6) -> fold(2) -> readlane
  //        -> rcp -> {o, u}(1) -> t(2) -> w'(3).
  // Fill: kh += o_prev (16 pk-fma) issues inside the reduce window.
  const f2 one = (f2)(1.0f);
  for (int it = 0; it < k; ++it) {
    // in-lane tree to TWO f2 partials (2 hops)
    f2 s0 = w[0] + w[1];
    f2 s1 = w[2] + w[3];
    f2 s2 = w[4] + w[5];
    f2 s3 = w[6] + w[7];
    f2 sA = s0 + s1;
    f2 sB = s2 + s3;
    // 4 independent cross-lane chains (interleaved issue, depth 6)
    float a = sA.x, c = sA.y, d = sB.x, e = sB.y;
    a = dpp_sum_step<0x111>(a); c = dpp_sum_step<0x111>(c);
    d = dpp_sum_step<0x111>(d); e = dpp_sum_step<0x111>(e);
    a = dpp_sum_step<0x112>(a); c = dpp_sum_step<0x112>(c);
    d = dpp_sum_step<0x112>(d); e = dpp_sum_step<0x112>(e);
    a = dpp_sum_step<0x114>(a); c = dpp_sum_step<0x114>(c);
    d = dpp_sum_step<0x114>(d); e = dpp_sum_step<0x114>(e);
    a = dpp_sum_step<0x118>(a); c = dpp_sum_step<0x118>(c);
    d = dpp_sum_step<0x118>(d); e = dpp_sum_step<0x118>(e);
    a = dpp_sum_step<0x142>(a); c = dpp_sum_step<0x142>(c);
    d = dpp_sum_step<0x142>(d); e = dpp_sum_step<0x142>(e);
    a = dpp_sum_step<0x143>(a); c = dpp_sum_step<0x143>(c);
    d = dpp_sum_step<0x143>(d); e = dpp_sum_step<0x143>(e);
    // kh += o_prev — independent of the chains above; fills their shadow
#pragma unroll
    for (int p = 0; p < 8; ++p) kh[p] += o[p];
    // fold (2 hops) + broadcast + rcp
    const float tot = (a + c) + (d + e);
    const float S = __int_as_float(
        __builtin_amdgcn_readlane(__float_as_int(tot), 63));
    const float rinv = __builtin_amdgcn_rcpf(S);
    f2 rv;
    rv.x = rinv;
    rv.y = rinv;
    // o = w*rinv (1 hop, off-chain afterwards); w <- w*(1-o)^2 (3 hops)
#pragma unroll
    for (int p = 0; p < 8; ++p) o[p] = w[p] * rv;
#pragma unroll
    for (int p = 0; p < 8; ++p) {
      const f2 u = __builtin_elementwise_fma(-w[p], rv, one);
      const f2 t = w[p] * u;
      w[p] = t * u;
    }
  }

  // --- final o accumulation + store
#pragma unroll
  for (int p = 0; p < 8; ++p) {
    kh[p] += o[p];
    out[base + (2 * p * 64 + lane) * 4] = kh[p].x;
    out[base + ((2 * p + 1) * 64 + lane) * 4] = kh[p].y;
  }
}

extern "C" void kernel_launch(void* const* d_in, const int* in_sizes, int n_in,
                              void* d_out, int out_size, void* d_ws, size_t ws_size,
                              hipStream_t stream) {
  const float* att = (const float*)d_in[0];
  const int* kp = (const int*)d_in[1];
  float* out = (float*)d_out;
  const int cols = out_size / N_NODES;  // 1024 columns, one wave each
  Sampler_72619307040792_kernel<<<cols, 64, 0, stream>>>(att, kp, out);
}

// Round 9
// 33.287 us; speedup vs baseline: 1.3579x; 1.3579x over previous
//
#include <hip/hip_runtime.h>
#include <math.h>

// Sampler: iterative Gumbel-softmax relaxed top-k.
// att: [B=256, N=1024, M=4] f32; k=128; out: khot [B,N,M] f32.
// One WAVE per (b,m) column (64 lanes x 16 elems as 8 packed float2).
// R6 structure (best: 31.8us) + ONE change: the cross-lane reduction uses
// FUSED v_add_f32+DPP (1 instr/step, canonical AMD 64-lane sum sequence)
// instead of update_dpp builtin (mov_dpp + add = 2 dependent instrs/step).
// DPP src hazards are software-managed -> explicit s_nop 1 between steps.
// w carries exp(2*ag - M0) exactly (verified R4-R8).
// PRNG: JAX threefry2x32 key (0,42), partitionable: counter (0,i),
// bits = out0 ^ out1 (verified R4).

#define N_NODES 1024

typedef float f2 __attribute__((ext_vector_type(2)));

__device__ __forceinline__ unsigned rotl32(unsigned x, int r) {
  return (x << r) | (x >> (32 - r));
}

// JAX/Random123 Threefry-2x32, 20 rounds.
__device__ __forceinline__ void threefry2x32(unsigned k0, unsigned k1,
                                             unsigned& x0, unsigned& x1) {
  const unsigned ks0 = k0, ks1 = k1, ks2 = k0 ^ k1 ^ 0x1BD11BDAu;
  x0 += ks0; x1 += ks1;
  x0 += x1; x1 = rotl32(x1, 13); x1 ^= x0;
  x0 += x1; x1 = rotl32(x1, 15); x1 ^= x0;
  x0 += x1; x1 = rotl32(x1, 26); x1 ^= x0;
  x0 += x1; x1 = rotl32(x1, 6);  x1 ^= x0;
  x0 += ks1; x1 += ks2 + 1u;
  x0 += x1; x1 = rotl32(x1, 17); x1 ^= x0;
  x0 += x1; x1 = rotl32(x1, 29); x1 ^= x0;
  x0 += x1; x1 = rotl32(x1, 16); x1 ^= x0;
  x0 += x1; x1 = rotl32(x1, 24); x1 ^= x0;
  x0 += ks2; x1 += ks0 + 2u;
  x0 += x1; x1 = rotl32(x1, 13); x1 ^= x0;
  x0 += x1; x1 = rotl32(x1, 15); x1 ^= x0;
  x0 += x1; x1 = rotl32(x1, 26); x1 ^= x0;
  x0 += x1; x1 = rotl32(x1, 6);  x1 ^= x0;
  x0 += ks0; x1 += ks1 + 3u;
  x0 += x1; x1 = rotl32(x1, 17); x1 ^= x0;
  x0 += x1; x1 = rotl32(x1, 29); x1 ^= x0;
  x0 += x1; x1 = rotl32(x1, 16); x1 ^= x0;
  x0 += x1; x1 = rotl32(x1, 24); x1 ^= x0;
  x0 += ks1; x1 += ks2 + 4u;
  x0 += x1; x1 = rotl32(x1, 13); x1 ^= x0;
  x0 += x1; x1 = rotl32(x1, 15); x1 ^= x0;
  x0 += x1; x1 = rotl32(x1, 26); x1 ^= x0;
  x0 += x1; x1 = rotl32(x1, 6);  x1 ^= x0;
  x0 += ks2; x1 += ks0 + 5u;
}

// Canonical 64-lane DPP sum with FUSED add+dpp (1 instr/step).
// After the sequence lane 63 holds the full sum; readlane broadcasts.
// s_nop 1 = 2 wait states, covering the VALU->DPP-source hazard.
__device__ __forceinline__ float wave_sum64_fused(float v) {
  asm("s_nop 1\n\t"
      "v_add_f32 %0, %0, %0 row_shr:1 bound_ctrl:0\n\t"
      "s_nop 1\n\t"
      "v_add_f32 %0, %0, %0 row_shr:2 bound_ctrl:0\n\t"
      "s_nop 1\n\t"
      "v_add_f32 %0, %0, %0 row_shr:4 bound_ctrl:0\n\t"
      "s_nop 1\n\t"
      "v_add_f32 %0, %0, %0 row_shr:8 bound_ctrl:0\n\t"
      "s_nop 1\n\t"
      "v_add_f32 %0, %0, %0 row_bcast:15 row_mask:0xa bound_ctrl:0\n\t"
      "s_nop 1\n\t"
      "v_add_f32 %0, %0, %0 row_bcast:31 row_mask:0xc bound_ctrl:0\n\t"
      "s_nop 1"
      : "+v"(v));
  return __int_as_float(__builtin_amdgcn_readlane(__float_as_int(v), 63));
}

// max variant (used once in the prologue; builtin form is fine there)
template <int CTRL>
__device__ __forceinline__ float dpp_max_step(float v) {
  int iv = __float_as_int(v);
  int t = __builtin_amdgcn_update_dpp(iv, iv, CTRL, 0xf, 0xf, false);
  return fmaxf(v, __int_as_float(t));
}
__device__ __forceinline__ float wave_max64(float v) {
  v = dpp_max_step<0x111>(v);
  v = dpp_max_step<0x112>(v);
  v = dpp_max_step<0x114>(v);
  v = dpp_max_step<0x118>(v);
  v = dpp_max_step<0x142>(v);
  v = dpp_max_step<0x143>(v);
  return __int_as_float(__builtin_amdgcn_readlane(__float_as_int(v), 63));
}

__global__ __launch_bounds__(64, 1)
void Sampler_72619307040792_kernel(const float* __restrict__ att,
                                   const int* __restrict__ kp,
                                   float* __restrict__ out) {
  const int col = blockIdx.x;        // 0..1023 = b*4 + m; ONE wave per column
  const int b = col >> 2;
  const int m = col & 3;
  const int lane = threadIdx.x;      // 64 threads = 1 wave
  const int k = *kp;

  const float EPS = __uint_as_float(0x00800000u);  // f32 tiny (normal min)
  const int base = b * 4096 + m;     // + n*4 indexes element n of this column

  float g[16];
  f2 w[8], kh[8];

  // --- init: att + Gumbel noise (threefry partitionable, bits = x0^x1), x2
#pragma unroll
  for (int j = 0; j < 16; ++j) {
    const int n = j * 64 + lane;
    const unsigned idx = (unsigned)(base + n * 4);
    unsigned c0 = 0u, c1 = idx;
    threefry2x32(0u, 42u, c0, c1);
    const unsigned bits = c0 ^ c1;
    const float u = __uint_as_float((bits >> 9) | 0x3F800000u) - 1.0f;
    const float gum = -logf(-logf(u + EPS));
    g[j] = 2.0f * (att[idx] + gum);
  }

  // --- column max M0 (uniform shift; exact softmax equivalence)
  float mx = g[0];
#pragma unroll
  for (int j = 1; j < 16; ++j) mx = fmaxf(mx, g[j]);
  mx = wave_max64(mx);

  // --- w = exp(g - M0) packed; kh = 0
#pragma unroll
  for (int p = 0; p < 8; ++p) {
    f2 t;
    t.x = expf(g[2 * p] - mx);
    t.y = expf(g[2 * p + 1] - mx);
    w[p] = t;
    kh[p] = (f2)(0.0f);
  }

  // --- k iterations (R6 rotated form):
  //   S = sum w; rinv = rcp(S); kh += w*rinv; w *= (1 - w*rinv)^2
  const f2 one = (f2)(1.0f);
  for (int it = 0; it < k; ++it) {
    // in-lane tree: 8 f2 -> 1 f2 (3 packed hops) -> scalar fold (1 hop)
    f2 s0 = w[0] + w[1];
    f2 s1 = w[2] + w[3];
    f2 s2 = w[4] + w[5];
    f2 s3 = w[6] + w[7];
    f2 sA = s0 + s1;
    f2 sB = s2 + s3;
    f2 sC = sA + sB;
    float sv = sC.x + sC.y;
    // cross-lane: 6 fused dpp-adds + readlane(63); rcp off the result
    const float S = wave_sum64_fused(sv);
    const float rinv = __builtin_amdgcn_rcpf(S);
    f2 rv;
    rv.x = rinv;
    rv.y = rinv;
    // kh += w*rinv (old w), then w <- w*(1-w*rinv)^2
#pragma unroll
    for (int p = 0; p < 8; ++p)
      kh[p] = __builtin_elementwise_fma(w[p], rv, kh[p]);
#pragma unroll
    for (int p = 0; p < 8; ++p) {
      const f2 u = __builtin_elementwise_fma(-w[p], rv, one);
      const f2 t = w[p] * u;
      w[p] = t * u;
    }
  }

  // --- store khot
#pragma unroll
  for (int p = 0; p < 8; ++p) {
    out[base + (2 * p * 64 + lane) * 4] = kh[p].x;
    out[base + ((2 * p + 1) * 64 + lane) * 4] = kh[p].y;
  }
}

extern "C" void kernel_launch(void* const* d_in, const int* in_sizes, int n_in,
                              void* d_out, int out_size, void* d_ws, size_t ws_size,
                              hipStream_t stream) {
  const float* att = (const float*)d_in[0];
  const int* kp = (const int*)d_in[1];
  float* out = (float*)d_out;
  const int cols = out_size / N_NODES;  // 1024 columns, one wave each
  Sampler_72619307040792_kernel<<<cols, 64, 0, stream>>>(att, kp, out);
}